// Round 5
// baseline (685.258 us; speedup 1.0000x reference)
//
#include <hip/hip_runtime.h>
#include <stdint.h>

#define N_NODES 50000
#define N_EDGES 800000
#define N_PATHS 3
#define N_HEADS 4
#define IN_F 256
#define BN_EPS 1e-5f
#define NEG_SLOPE 0.2f
#define CAP 48           // slot capacity per node; Poisson(16) => P(deg>48) ~ 3e-11
#define TOT_EDGES (N_PATHS * N_EDGES)   // 2400000

typedef short bf16x8 __attribute__((ext_vector_type(8)));
typedef float f32x4 __attribute__((ext_vector_type(4)));

__device__ inline unsigned short f2bf(float f) {
  unsigned u = __float_as_uint(f);
  unsigned r = (u + 0x7FFFu + ((u >> 16) & 1u)) >> 16;
  return (unsigned short)r;
}
__device__ inline float bf2f(unsigned short s) {
  return __uint_as_float(((unsigned)s) << 16);
}
__device__ inline float bfl(unsigned u) { return __uint_as_float(u << 16); }
__device__ inline float bfh(unsigned u) { return __uint_as_float(u & 0xFFFF0000u); }

// ---------------- zero fill ----------------
__global__ __launch_bounds__(256) void k_zero(unsigned* p, int nwords) {
  int i = blockIdx.x * 256 + threadIdx.x;
  if (i < nwords) p[i] = 0u;
}

// ---------------- h -> bf16 ----------------
__global__ __launch_bounds__(256) void k_convert_h(const float* __restrict__ h,
                                                   unsigned short* __restrict__ hbf) {
  int idx = (blockIdx.x * 256 + threadIdx.x) * 4;
  float4 v = *(const float4*)(h + idx);
  unsigned u0 = (unsigned)f2bf(v.x) | ((unsigned)f2bf(v.y) << 16);
  unsigned u1 = (unsigned)f2bf(v.z) | ((unsigned)f2bf(v.w) << 16);
  *(uint2*)(hbf + idx) = make_uint2(u0, u1);
}

// ---------------- W -> bf16, transposed to [n][k], all paths ----------------
__global__ __launch_bounds__(256) void k_convert_w(const float* __restrict__ fcw,
                                                   unsigned short* __restrict__ wbf) {
  __shared__ float sh[32][33];
  int bt = blockIdx.x;
  int p = bt >> 6;
  int tile = bt & 63;
  int tk = tile >> 3, tn = tile & 7;
  const float* base = fcw + (size_t)p * IN_F * IN_F;
  unsigned short* ob = wbf + (size_t)p * IN_F * IN_F;
  int c = threadIdx.x & 31, r0 = threadIdx.x >> 5;
  #pragma unroll
  for (int it = 0; it < 4; ++it) {
    int r = r0 + it * 8;
    sh[r][c] = base[(size_t)(tk * 32 + r) * IN_F + tn * 32 + c];
  }
  __syncthreads();
  #pragma unroll
  for (int it = 0; it < 4; ++it) {
    int r = r0 + it * 8;
    ob[(size_t)(tn * 32 + r) * IN_F + tk * 32 + c] = f2bf(sh[c][r]);
  }
}

// ---------------- single-pass binning (R5): replaces k_bin + k_fine ----------------
// k_fine ran only 147 blocks (<1/CU, latency-bound); the 2-phase structure existed
// solely to localize slot writes. One pass: global atomicAdd on per-node cursors
// (150K distinct counters, ~16-deep contention -> fine at device atomic rate),
// scattered 2B slot stores absorbed by L2/L3 (byte-granular dirty masks merge
// cross-XCD same-line writes safely).
__global__ __launch_bounds__(256) void k_bin2(const int* __restrict__ src,
                                              const int* __restrict__ dst,
                                              int* __restrict__ cnt,
                                              unsigned short* __restrict__ slots) {
  int gid = blockIdx.x * 256 + threadIdx.x;
  if (gid >= TOT_EDGES) return;
  int s = src[gid], d = dst[gid];
  int p = (gid >= 2 * N_EDGES) ? 2 : ((gid >= N_EDGES) ? 1 : 0);
  int b = p * N_NODES + d;
  int pos = atomicAdd(&cnt[b], 1);
  if (pos < CAP) slots[(size_t)b * CAP + pos] = (unsigned short)s;
}

// ---------------- fused GEMM (all paths): feat + el/er epilogue ----------------
// block: 64 rows x 256 cols of one path. A staged once; B streamed per 64-col chunk.
// chunk c == head c. el/er computed from fp32 acc via in-wave reduction.
__global__ __launch_bounds__(256) void k_gemm(const unsigned short* __restrict__ hbf,
                                              const unsigned short* __restrict__ wbf,
                                              const float* __restrict__ attl,
                                              const float* __restrict__ attr,
                                              unsigned short* __restrict__ featbf,
                                              float* __restrict__ el,
                                              float* __restrict__ erd) {
  __shared__ unsigned short As[64 * 264];
  __shared__ unsigned short Bs[64 * 264];
  __shared__ float sal[256];
  __shared__ float sar[256];
  int m0 = blockIdx.x * 64;
  int p = blockIdx.y;
  int tid = threadIdx.x;
  const unsigned short* wptr = wbf + (size_t)p * IN_F * IN_F;

  sal[tid] = attl[p * 256 + tid];
  sar[tid] = attr[p * 256 + tid];
  for (int i = tid; i < 2048; i += 256) {
    int r = i >> 5, g = i & 31;
    int gr = m0 + r;
    uint4 v = make_uint4(0, 0, 0, 0);
    if (gr < N_NODES) v = *(const uint4*)(hbf + (size_t)gr * IN_F + g * 8);
    *(uint4*)(&As[r * 264 + g * 8]) = v;
  }

  int wv = tid >> 6, lane = tid & 63;
  int l15 = lane & 15, quad = lane >> 4;
  const unsigned short* arow = &As[(wv * 16 + l15) * 264];
  size_t featbase = (size_t)p * N_NODES * IN_F;
  float* elp = el + (size_t)p * N_NODES * 4;
  float* erdp = erd + (size_t)p * N_NODES * 8;

  for (int c = 0; c < 4; ++c) {
    __syncthreads();  // A ready (c=0) / prev-chunk Bs reads done (c>0)
    for (int i = tid; i < 2048; i += 256) {
      int r = i >> 5, g = i & 31;
      *(uint4*)(&Bs[r * 264 + g * 8]) =
          *(const uint4*)(wptr + (size_t)(c * 64 + r) * IN_F + g * 8);
    }
    __syncthreads();

    f32x4 acc[4];
    #pragma unroll
    for (int i = 0; i < 4; ++i) acc[i] = (f32x4){0.f, 0.f, 0.f, 0.f};
    #pragma unroll
    for (int kb = 0; kb < 8; ++kb) {
      bf16x8 a = *(const bf16x8*)(arow + kb * 32 + quad * 8);
      #pragma unroll
      for (int nn = 0; nn < 4; ++nn) {
        bf16x8 b = *(const bf16x8*)(&Bs[(nn * 16 + l15) * 264 + kb * 32 + quad * 8]);
        acc[nn] = __builtin_amdgcn_mfma_f32_16x16x32_bf16(a, b, acc[nn], 0, 0, 0);
      }
    }
    // feat store (C/D layout: col = lane&15, row = quad*4+reg)
    #pragma unroll
    for (int nn = 0; nn < 4; ++nn)
      #pragma unroll
      for (int rg = 0; rg < 4; ++rg) {
        int grow = m0 + wv * 16 + quad * 4 + rg;
        if (grow < N_NODES)
          featbf[featbase + (size_t)grow * IN_F + c * 64 + nn * 16 + l15] = f2bf(acc[nn][rg]);
      }
    // el/er for head c: per-row dot over the 64 chunk cols
    #pragma unroll
    for (int rg = 0; rg < 4; ++rg) {
      float a = 0.f, b = 0.f;
      #pragma unroll
      for (int nn = 0; nn < 4; ++nn) {
        float v = acc[nn][rg];
        int col = c * 64 + nn * 16 + l15;
        a += v * sal[col];
        b += v * sar[col];
      }
      a += __shfl_xor(a, 1); a += __shfl_xor(a, 2); a += __shfl_xor(a, 4); a += __shfl_xor(a, 8);
      b += __shfl_xor(b, 1); b += __shfl_xor(b, 2); b += __shfl_xor(b, 4); b += __shfl_xor(b, 8);
      int grow = m0 + wv * 16 + quad * 4 + rg;
      if (l15 == 0 && grow < N_NODES) {
        elp[(size_t)grow * 4 + c] = a;
        erdp[(size_t)grow * 8 + c] = b;
      }
    }
  }
}

// ---------------- gather: wave-per-node, half-wave-per-edge, barrier-free ----------------
// At its measured memory-path floor (~171us, R3/R4 structurally different loops
// both land there): 1.23 GB mandatory random 512B row reads @ ~7.2 TB/s mixed
// L2/L3/HBM delivery. Unchanged this round.
__global__ __launch_bounds__(256) void k_gather(const int* __restrict__ cnt,
                                                const unsigned short* __restrict__ slots,
                                                const float* __restrict__ el,
                                                float* __restrict__ erd,
                                                const unsigned short* __restrict__ featbf,
                                                unsigned short* __restrict__ outbuf) {
  __shared__ float xs[4][4][CAP];     // [wave][head][edge] softmax numerators
  __shared__ unsigned soff[4][CAP];   // [wave][edge] feat byte offsets
  int p = blockIdx.y;
  int tid = threadIdx.x;
  int wv = tid >> 6, lane = tid & 63;
  int node = blockIdx.x * 4 + wv;
  int b = p * N_NODES + node;
  int half = lane >> 5, lane32 = lane & 31;
  int head = lane32 >> 3;        // phase-B head: cols lane32*8..+7 in head lane32>>3
  int m = cnt[b];
  if (m > CAP) m = CAP;
  const float* elp = el + (size_t)p * N_NODES * 4;
  float* erdp = erd + (size_t)p * N_NODES * 8;
  const unsigned short* sl = slots + (size_t)b * CAP;
  const char* fp_ = (const char*)featbf + (size_t)p * N_NODES * IN_F * 2 + lane32 * 16;

  // ---- phase A: lanes (headA=lane>>4, e0=lane&15) cover all (head, edge) pairs ----
  {
    int headA = lane >> 4;
    float ern = erdp[(size_t)node * 8 + headA];
    for (int e = lane & 15; e < m; e += 16) {
      int s = (int)sl[e];
      if (headA == 0) soff[wv][e] = (unsigned)s * (unsigned)(IN_F * 2);
      float ev = elp[s * 4 + headA] + ern;
      ev = ev > 0.f ? ev : NEG_SLOPE * ev;
      xs[wv][headA][e] = __expf(ev);
    }
  }
  // same-wave LDS producer->consumer: in-order DS pipe, compiler waitcnts; no barrier.

  // ---- phase B: this half's edges (parity = half), 4-deep unroll, dwordx4 loads ----
  float a0 = 0.f, a1 = 0.f, a2 = 0.f, a3 = 0.f;
  float a4 = 0.f, a5 = 0.f, a6 = 0.f, a7 = 0.f, den = 0.f;
  int i = half;
  for (; i + 6 < m; i += 8) {
    unsigned o0 = soff[wv][i], o1 = soff[wv][i + 2], o2 = soff[wv][i + 4], o3 = soff[wv][i + 6];
    float x0 = xs[wv][head][i], x1 = xs[wv][head][i + 2];
    float x2 = xs[wv][head][i + 4], x3 = xs[wv][head][i + 6];
    uint4 f0 = *(const uint4*)(fp_ + o0);
    uint4 f1 = *(const uint4*)(fp_ + o1);
    uint4 f2 = *(const uint4*)(fp_ + o2);
    uint4 f3 = *(const uint4*)(fp_ + o3);
    den += (x0 + x1) + (x2 + x3);
    a0 += x0 * bfl(f0.x) + x1 * bfl(f1.x) + x2 * bfl(f2.x) + x3 * bfl(f3.x);
    a1 += x0 * bfh(f0.x) + x1 * bfh(f1.x) + x2 * bfh(f2.x) + x3 * bfh(f3.x);
    a2 += x0 * bfl(f0.y) + x1 * bfl(f1.y) + x2 * bfl(f2.y) + x3 * bfl(f3.y);
    a3 += x0 * bfh(f0.y) + x1 * bfh(f1.y) + x2 * bfh(f2.y) + x3 * bfh(f3.y);
    a4 += x0 * bfl(f0.z) + x1 * bfl(f1.z) + x2 * bfl(f2.z) + x3 * bfl(f3.z);
    a5 += x0 * bfh(f0.z) + x1 * bfh(f1.z) + x2 * bfh(f2.z) + x3 * bfh(f3.z);
    a6 += x0 * bfl(f0.w) + x1 * bfl(f1.w) + x2 * bfl(f2.w) + x3 * bfl(f3.w);
    a7 += x0 * bfh(f0.w) + x1 * bfh(f1.w) + x2 * bfh(f2.w) + x3 * bfh(f3.w);
  }
  for (; i + 2 < m; i += 4) {
    unsigned o0 = soff[wv][i], o1 = soff[wv][i + 2];
    float x0 = xs[wv][head][i], x1 = xs[wv][head][i + 2];
    uint4 f0 = *(const uint4*)(fp_ + o0);
    uint4 f1 = *(const uint4*)(fp_ + o1);
    den += x0 + x1;
    a0 += x0 * bfl(f0.x) + x1 * bfl(f1.x);
    a1 += x0 * bfh(f0.x) + x1 * bfh(f1.x);
    a2 += x0 * bfl(f0.y) + x1 * bfl(f1.y);
    a3 += x0 * bfh(f0.y) + x1 * bfh(f1.y);
    a4 += x0 * bfl(f0.z) + x1 * bfl(f1.z);
    a5 += x0 * bfh(f0.z) + x1 * bfh(f1.z);
    a6 += x0 * bfl(f0.w) + x1 * bfl(f1.w);
    a7 += x0 * bfh(f0.w) + x1 * bfh(f1.w);
  }
  for (; i < m; i += 2) {
    unsigned o0 = soff[wv][i];
    float x0 = xs[wv][head][i];
    uint4 f = *(const uint4*)(fp_ + o0);
    den += x0;
    a0 += x0 * bfl(f.x);
    a1 += x0 * bfh(f.x);
    a2 += x0 * bfl(f.y);
    a3 += x0 * bfh(f.y);
    a4 += x0 * bfl(f.z);
    a5 += x0 * bfh(f.z);
    a6 += x0 * bfl(f.w);
    a7 += x0 * bfh(f.w);
  }

  // ---- merge halves + epilogue ----
  den += __shfl_xor(den, 32);
  a0 += __shfl_xor(a0, 32);
  a1 += __shfl_xor(a1, 32);
  a2 += __shfl_xor(a2, 32);
  a3 += __shfl_xor(a3, 32);
  a4 += __shfl_xor(a4, 32);
  a5 += __shfl_xor(a5, 32);
  a6 += __shfl_xor(a6, 32);
  a7 += __shfl_xor(a7, 32);
  if (half == 0) {
    float inv = den > 0.f ? 1.f / den : 0.f;
    float o0 = fmaxf(a0 * inv, 0.f), o1 = fmaxf(a1 * inv, 0.f);
    float o2 = fmaxf(a2 * inv, 0.f), o3 = fmaxf(a3 * inv, 0.f);
    float o4 = fmaxf(a4 * inv, 0.f), o5 = fmaxf(a5 * inv, 0.f);
    float o6 = fmaxf(a6 * inv, 0.f), o7 = fmaxf(a7 * inv, 0.f);
    uint4 u;
    u.x = (unsigned)f2bf(o0) | ((unsigned)f2bf(o1) << 16);
    u.y = (unsigned)f2bf(o2) | ((unsigned)f2bf(o3) << 16);
    u.z = (unsigned)f2bf(o4) | ((unsigned)f2bf(o5) << 16);
    u.w = (unsigned)f2bf(o6) | ((unsigned)f2bf(o7) << 16);
    *(uint4*)(outbuf + (size_t)b * IN_F + lane32 * 8) = u;
    if ((lane32 & 7) == 0) erdp[(size_t)node * 8 + 4 + head] = inv;
  }
}

// ---------------- attention coefficients (all paths): alpha = exp(e)*invdenom, mean heads ----------------
__global__ __launch_bounds__(256) void k_attn(const int* __restrict__ src, const int* __restrict__ dst,
                                              const float* __restrict__ el,
                                              const float* __restrict__ erd,
                                              float* __restrict__ attn_out) {
  int eid = blockIdx.x * 256 + threadIdx.x;
  int p = eid / N_EDGES;
  int s = src[eid], t = dst[eid];
  const float* elp = el + (size_t)p * N_NODES * 4;
  const float* erdp = erd + (size_t)p * N_NODES * 8;
  float4 a = *(const float4*)(elp + (size_t)s * 4);
  float4 b = *(const float4*)(erdp + (size_t)t * 8);
  float4 idn = *(const float4*)(erdp + (size_t)t * 8 + 4);
  float4 e;
  e.x = a.x + b.x; e.x = e.x > 0.f ? e.x : NEG_SLOPE * e.x;
  e.y = a.y + b.y; e.y = e.y > 0.f ? e.y : NEG_SLOPE * e.y;
  e.z = a.z + b.z; e.z = e.z > 0.f ? e.z : NEG_SLOPE * e.z;
  e.w = a.w + b.w; e.w = e.w > 0.f ? e.w : NEG_SLOPE * e.w;
  attn_out[eid] = 0.25f * (__expf(e.x) * idn.x + __expf(e.y) * idn.y +
                           __expf(e.z) * idn.z + __expf(e.w) * idn.w);
}

// ---------------- BN column stats, all 3 paths in one pass (h read once) ----------------
__global__ __launch_bounds__(256) void k_bnstats3(const unsigned short* __restrict__ outbuf,
                                                  const float* __restrict__ h,
                                                  float* __restrict__ colsum, float* __restrict__ colsq) {
  int t = threadIdx.x;
  float s0 = 0.f, q0 = 0.f, s1 = 0.f, q1 = 0.f, s2 = 0.f, q2 = 0.f;
  for (int r = blockIdx.x; r < N_NODES; r += gridDim.x) {
    float hv = h[(size_t)r * IN_F + t];
    float v0 = bf2f(outbuf[(size_t)r * IN_F + t]) + hv;
    float v1 = bf2f(outbuf[((size_t)N_NODES + r) * IN_F + t]) + hv;
    float v2 = bf2f(outbuf[((size_t)2 * N_NODES + r) * IN_F + t]) + hv;
    s0 += v0; q0 += v0 * v0;
    s1 += v1; q1 += v1 * v1;
    s2 += v2; q2 += v2 * v2;
  }
  atomicAdd(&colsum[t], s0);
  atomicAdd(&colsq[t], q0);
  atomicAdd(&colsum[256 + t], s1);
  atomicAdd(&colsq[256 + t], q1);
  atomicAdd(&colsum[512 + t], s2);
  atomicAdd(&colsq[512 + t], q2);
}

// ---------------- BN apply + semantic pooling + out_w, one pass ----------------
// R5: k_wout fused here (spm/ssum already computed; writes the [N,3] weights).
__global__ __launch_bounds__(256) void k_bnapply3(const unsigned short* __restrict__ outbuf,
                                                  const float* __restrict__ h,
                                                  const float* __restrict__ colsum, const float* __restrict__ colsq,
                                                  const float* __restrict__ gamma, const float* __restrict__ beta,
                                                  const float* __restrict__ pmask,
                                                  float* __restrict__ pooled,
                                                  float* __restrict__ wout) {
  __shared__ float spm[3];
  int n = blockIdx.x, t = threadIdx.x;
  if (t < 3) spm[t] = pmask[n * 3 + t];
  __syncthreads();
  float ssum = spm[0] + spm[1] + spm[2];
  if (t < 3) wout[n * 3 + t] = spm[t] / ssum;
  const float invN = 1.f / (float)N_NODES;
  float hv = h[(size_t)n * IN_F + t];
  float g = gamma[t], bt = beta[t];
  float pv = 0.f;
  #pragma unroll
  for (int p = 0; p < 3; ++p) {
    float mu = colsum[p * 256 + t] * invN;
    float var = colsq[p * 256 + t] * invN - mu * mu;
    float rs = rsqrtf(var + BN_EPS);
    float v = bf2f(outbuf[((size_t)p * N_NODES + n) * IN_F + t]) + hv;
    float emb = g * (v - mu) * rs + bt;
    pv += (spm[p] / ssum) * emb;
  }
  pooled[(size_t)n * IN_F + t] = pv;
}

extern "C" void kernel_launch(void* const* d_in, const int* in_sizes, int n_in,
                              void* d_out, int out_size, void* d_ws, size_t ws_size,
                              hipStream_t stream) {
  const float* h     = (const float*)d_in[0];
  const float* pmask = (const float*)d_in[1];
  const int*   src   = (const int*)d_in[2];
  const int*   dst   = (const int*)d_in[3];
  const float* fcw   = (const float*)d_in[4];
  const float* attl  = (const float*)d_in[5];
  const float* attr  = (const float*)d_in[6];
  const float* gamma = (const float*)d_in[7];
  const float* beta  = (const float*)d_in[8];

  float* out_pooled = (float*)d_out;
  float* out_w = out_pooled + (size_t)N_NODES * IN_F;
  float* out_attn = out_w + (size_t)N_NODES * N_PATHS;

  char* wp = (char*)d_ws;
  auto carve = [&](size_t bytes) {
    char* r = wp;
    wp += (bytes + 255) & ~(size_t)255;
    return r;
  };
  unsigned short* hbf    = (unsigned short*)carve((size_t)N_NODES * IN_F * 2);          // 25.6 MB
  unsigned short* featbf = (unsigned short*)carve((size_t)N_PATHS * N_NODES * IN_F * 2); // 76.8 MB
  unsigned short* wbf    = (unsigned short*)carve((size_t)N_PATHS * IN_F * IN_F * 2);    // 0.4 MB
  unsigned short* outbuf = (unsigned short*)carve((size_t)N_PATHS * N_NODES * IN_F * 2); // 76.8 MB
  float* el  = (float*)carve((size_t)N_PATHS * N_NODES * 4 * 4);                         // 2.4 MB
  float* erd = (float*)carve((size_t)N_PATHS * N_NODES * 8 * 4);                         // 4.8 MB
  unsigned short* slots = (unsigned short*)carve((size_t)N_PATHS * N_NODES * CAP * 2);   // 14.4 MB
  // zero-region: cnt[3][N], colsum[3][256], colsq[3][256]
  char* zbase = wp;
  int* cnt = (int*)carve((size_t)N_PATHS * N_NODES * 4);                                  // 0.6 MB
  float* colsum = (float*)carve((size_t)N_PATHS * IN_F * 4);
  float* colsq  = (float*)carve((size_t)N_PATHS * IN_F * 4);
  int zero_words = (int)((wp - zbase) / 4);

  k_convert_h<<<(N_NODES * IN_F) / 1024, 256, 0, stream>>>(h, hbf);
  k_convert_w<<<N_PATHS * 64, 256, 0, stream>>>(fcw, wbf);
  k_zero<<<(zero_words + 255) / 256, 256, 0, stream>>>((unsigned*)zbase, zero_words);
  k_bin2<<<(TOT_EDGES + 255) / 256, 256, 0, stream>>>(src, dst, cnt, slots);
  k_gemm<<<dim3((N_NODES + 63) / 64, N_PATHS), 256, 0, stream>>>(hbf, wbf, attl, attr,
                                                                 featbf, el, erd);
  k_gather<<<dim3(N_NODES / 4, N_PATHS), 256, 0, stream>>>(cnt, slots, el, erd, featbf, outbuf);
  k_attn<<<TOT_EDGES / 256, 256, 0, stream>>>(src, dst, el, erd, out_attn);
  k_bnstats3<<<512, 256, 0, stream>>>(outbuf, h, colsum, colsq);
  k_bnapply3<<<N_NODES, 256, 0, stream>>>(outbuf, h, colsum, colsq, gamma, beta, pmask,
                                          out_pooled, out_w);
}

// Round 6
// 612.348 us; speedup vs baseline: 1.1191x; 1.1191x over previous
//
#include <hip/hip_runtime.h>
#include <stdint.h>

#define N_NODES 50000
#define N_EDGES 800000
#define N_PATHS 3
#define N_HEADS 4
#define IN_F 256
#define BN_EPS 1e-5f
#define NEG_SLOPE 0.2f
#define CAP 48           // slot capacity per node; Poisson(16) => P(deg>48) ~ 3e-11
#define NB_PER_PATH 49   // coarse buckets of 1024 nodes
#define NB_TOT (N_PATHS * NB_PER_PATH)  // 147
#define REC_CAP 18432
#define BIN_EPB 4096
#define TOT_EDGES (N_PATHS * N_EDGES)   // 2400000
#define BIN_BLOCKS ((TOT_EDGES + BIN_EPB - 1) / BIN_EPB)  // 586

typedef short bf16x8 __attribute__((ext_vector_type(8)));
typedef float f32x4 __attribute__((ext_vector_type(4)));

__device__ inline unsigned short f2bf(float f) {
  unsigned u = __float_as_uint(f);
  unsigned r = (u + 0x7FFFu + ((u >> 16) & 1u)) >> 16;
  return (unsigned short)r;
}
__device__ inline float bf2f(unsigned short s) {
  return __uint_as_float(((unsigned)s) << 16);
}
__device__ inline float bfl(unsigned u) { return __uint_as_float(u << 16); }
__device__ inline float bfh(unsigned u) { return __uint_as_float(u & 0xFFFF0000u); }

// ---------------- zero fill ----------------
__global__ __launch_bounds__(256) void k_zero(unsigned* p, int nwords) {
  int i = blockIdx.x * 256 + threadIdx.x;
  if (i < nwords) p[i] = 0u;
}

// ---------------- h -> bf16 ----------------
__global__ __launch_bounds__(256) void k_convert_h(const float* __restrict__ h,
                                                   unsigned short* __restrict__ hbf) {
  int idx = (blockIdx.x * 256 + threadIdx.x) * 4;
  float4 v = *(const float4*)(h + idx);
  unsigned u0 = (unsigned)f2bf(v.x) | ((unsigned)f2bf(v.y) << 16);
  unsigned u1 = (unsigned)f2bf(v.z) | ((unsigned)f2bf(v.w) << 16);
  *(uint2*)(hbf + idx) = make_uint2(u0, u1);
}

// ---------------- W -> bf16, transposed to [n][k], all paths ----------------
__global__ __launch_bounds__(256) void k_convert_w(const float* __restrict__ fcw,
                                                   unsigned short* __restrict__ wbf) {
  __shared__ float sh[32][33];
  int bt = blockIdx.x;
  int p = bt >> 6;
  int tile = bt & 63;
  int tk = tile >> 3, tn = tile & 7;
  const float* base = fcw + (size_t)p * IN_F * IN_F;
  unsigned short* ob = wbf + (size_t)p * IN_F * IN_F;
  int c = threadIdx.x & 31, r0 = threadIdx.x >> 5;
  #pragma unroll
  for (int it = 0; it < 4; ++it) {
    int r = r0 + it * 8;
    sh[r][c] = base[(size_t)(tk * 32 + r) * IN_F + tn * 32 + c];
  }
  __syncthreads();
  #pragma unroll
  for (int it = 0; it < 4; ++it) {
    int r = r0 + it * 8;
    ob[(size_t)(tn * 32 + r) * IN_F + tk * 32 + c] = f2bf(sh[c][r]);
  }
}

// ---------------- bin phase 1 (R6 revert of R5 atomic binning): LDS histogram ->
// few global atomics -> coalesced record runs. Record now carries the EDGE id
// (20b) + dst-low (10b) so gather can emit attention coefs (k_attn fused away).
__global__ __launch_bounds__(256) void k_bin(const int* __restrict__ src, const int* __restrict__ dst,
                                             unsigned* __restrict__ gcurP, unsigned* __restrict__ grec) {
  __shared__ unsigned hist[NB_TOT];
  __shared__ unsigned lbase[NB_TOT];
  __shared__ unsigned gbase[NB_TOT];
  __shared__ unsigned lcur[NB_TOT];
  __shared__ unsigned scanbuf[256];
  __shared__ unsigned char sbuck[BIN_EPB];
  __shared__ unsigned stage[BIN_EPB];
  int t = threadIdx.x;
  int base = blockIdx.x * BIN_EPB;
  for (int i = t; i < NB_TOT; i += 256) { hist[i] = 0u; lcur[i] = 0u; }
  __syncthreads();

  unsigned rec[16];
  int bk[16];
  #pragma unroll
  for (int k = 0; k < 16; ++k) {
    int gid = base + t + k * 256;
    bk[k] = -1;
    if (gid < TOT_EDGES) {
      int d = dst[gid];
      int p = (gid >= 2 * N_EDGES) ? 2 : ((gid >= N_EDGES) ? 1 : 0);
      int b = p * NB_PER_PATH + (d >> 10);
      bk[k] = b;
      unsigned eid = (unsigned)(gid - p * N_EDGES);           // < 2^20
      rec[k] = ((unsigned)(d & 1023) << 22) | eid;
      atomicAdd(&hist[b], 1u);
    }
  }
  __syncthreads();
  for (int i = t; i < NB_TOT; i += 256)
    gbase[i] = hist[i] ? atomicAdd(&gcurP[i * 16], hist[i]) : 0u;
  scanbuf[t] = (t < NB_TOT) ? hist[t] : 0u;
  __syncthreads();
  for (int off = 1; off < 256; off <<= 1) {
    unsigned v = (t >= off) ? scanbuf[t - off] : 0u;
    __syncthreads();
    scanbuf[t] += v;
    __syncthreads();
  }
  if (t < NB_TOT) lbase[t] = scanbuf[t] - hist[t];
  __syncthreads();
  #pragma unroll
  for (int k = 0; k < 16; ++k) {
    if (bk[k] >= 0) {
      int b = bk[k];
      unsigned pos = atomicAdd(&lcur[b], 1u) + lbase[b];
      stage[pos] = rec[k];
      sbuck[pos] = (unsigned char)b;
    }
  }
  __syncthreads();
  int nblk = TOT_EDGES - base;
  if (nblk > BIN_EPB) nblk = BIN_EPB;
  for (int i = t; i < nblk; i += 256) {
    int b = sbuck[i];
    unsigned off = (unsigned)i - lbase[b];
    unsigned gpos = gbase[b] + off;
    if (gpos < REC_CAP) grec[(size_t)b * REC_CAP + gpos] = stage[i];
  }
}

// ---------------- bin phase 2: per coarse bucket, LDS cursors -> u32 eid slots + counts ----------------
__global__ __launch_bounds__(1024) void k_fine(const unsigned* __restrict__ gcurP,
                                               const unsigned* __restrict__ grec,
                                               unsigned* __restrict__ slots,
                                               int* __restrict__ cnt) {
  __shared__ unsigned cur[1024];
  int b = blockIdx.x;
  int p = b / NB_PER_PATH;
  int nb0 = (b % NB_PER_PATH) << 10;
  int t = threadIdx.x;
  cur[t] = 0u;
  __syncthreads();
  unsigned M = gcurP[b * 16];
  if (M > REC_CAP) M = REC_CAP;
  const unsigned* rb = grec + (size_t)b * REC_CAP;
  for (unsigned i = t; i < M; i += 1024) {
    unsigned r = rb[i];
    int node = r >> 22;
    unsigned eid = r & 0x3FFFFFu;
    unsigned pos = atomicAdd(&cur[node], 1u);
    if (pos < CAP)
      slots[((size_t)(p * N_NODES + nb0 + node)) * CAP + pos] = eid;
  }
  __syncthreads();
  int node = nb0 + t;
  if (node < N_NODES) cnt[p * N_NODES + node] = (int)cur[t];
}

// ---------------- fused GEMM (all paths): feat + el/er epilogue ----------------
__global__ __launch_bounds__(256) void k_gemm(const unsigned short* __restrict__ hbf,
                                              const unsigned short* __restrict__ wbf,
                                              const float* __restrict__ attl,
                                              const float* __restrict__ attr,
                                              unsigned short* __restrict__ featbf,
                                              float* __restrict__ el,
                                              float* __restrict__ erd) {
  __shared__ unsigned short As[64 * 264];
  __shared__ unsigned short Bs[64 * 264];
  __shared__ float sal[256];
  __shared__ float sar[256];
  int m0 = blockIdx.x * 64;
  int p = blockIdx.y;
  int tid = threadIdx.x;
  const unsigned short* wptr = wbf + (size_t)p * IN_F * IN_F;

  sal[tid] = attl[p * 256 + tid];
  sar[tid] = attr[p * 256 + tid];
  for (int i = tid; i < 2048; i += 256) {
    int r = i >> 5, g = i & 31;
    int gr = m0 + r;
    uint4 v = make_uint4(0, 0, 0, 0);
    if (gr < N_NODES) v = *(const uint4*)(hbf + (size_t)gr * IN_F + g * 8);
    *(uint4*)(&As[r * 264 + g * 8]) = v;
  }

  int wv = tid >> 6, lane = tid & 63;
  int l15 = lane & 15, quad = lane >> 4;
  const unsigned short* arow = &As[(wv * 16 + l15) * 264];
  size_t featbase = (size_t)p * N_NODES * IN_F;
  float* elp = el + (size_t)p * N_NODES * 4;
  float* erdp = erd + (size_t)p * N_NODES * 8;

  for (int c = 0; c < 4; ++c) {
    __syncthreads();  // A ready (c=0) / prev-chunk Bs reads done (c>0)
    for (int i = tid; i < 2048; i += 256) {
      int r = i >> 5, g = i & 31;
      *(uint4*)(&Bs[r * 264 + g * 8]) =
          *(const uint4*)(wptr + (size_t)(c * 64 + r) * IN_F + g * 8);
    }
    __syncthreads();

    f32x4 acc[4];
    #pragma unroll
    for (int i = 0; i < 4; ++i) acc[i] = (f32x4){0.f, 0.f, 0.f, 0.f};
    #pragma unroll
    for (int kb = 0; kb < 8; ++kb) {
      bf16x8 a = *(const bf16x8*)(arow + kb * 32 + quad * 8);
      #pragma unroll
      for (int nn = 0; nn < 4; ++nn) {
        bf16x8 b = *(const bf16x8*)(&Bs[(nn * 16 + l15) * 264 + kb * 32 + quad * 8]);
        acc[nn] = __builtin_amdgcn_mfma_f32_16x16x32_bf16(a, b, acc[nn], 0, 0, 0);
      }
    }
    // feat store (C/D layout: col = lane&15, row = quad*4+reg)
    #pragma unroll
    for (int nn = 0; nn < 4; ++nn)
      #pragma unroll
      for (int rg = 0; rg < 4; ++rg) {
        int grow = m0 + wv * 16 + quad * 4 + rg;
        if (grow < N_NODES)
          featbf[featbase + (size_t)grow * IN_F + c * 64 + nn * 16 + l15] = f2bf(acc[nn][rg]);
      }
    // el/er for head c: per-row dot over the 64 chunk cols
    #pragma unroll
    for (int rg = 0; rg < 4; ++rg) {
      float a = 0.f, b = 0.f;
      #pragma unroll
      for (int nn = 0; nn < 4; ++nn) {
        float v = acc[nn][rg];
        int col = c * 64 + nn * 16 + l15;
        a += v * sal[col];
        b += v * sar[col];
      }
      a += __shfl_xor(a, 1); a += __shfl_xor(a, 2); a += __shfl_xor(a, 4); a += __shfl_xor(a, 8);
      b += __shfl_xor(b, 1); b += __shfl_xor(b, 2); b += __shfl_xor(b, 4); b += __shfl_xor(b, 8);
      int grow = m0 + wv * 16 + quad * 4 + rg;
      if (l15 == 0 && grow < N_NODES) {
        elp[(size_t)grow * 4 + c] = a;
        erdp[(size_t)grow * 8 + c] = b;
      }
    }
  }
}

// ---------------- gather: wave-per-node, half-wave-per-edge, barrier-free ----------------
// R6: slots hold edge-ids; phase A derives s = src[eid]; phase C emits the
// attention coefficients (alpha = exp*inv, mean over heads) -> k_attn deleted.
__global__ __launch_bounds__(256) void k_gather(const int* __restrict__ cnt,
                                                const unsigned* __restrict__ slots,
                                                const int* __restrict__ src,
                                                const float* __restrict__ el,
                                                float* __restrict__ erd,
                                                const unsigned short* __restrict__ featbf,
                                                unsigned short* __restrict__ outbuf,
                                                float* __restrict__ attn_out) {
  __shared__ float xs[4][4][CAP];     // [wave][head][edge] softmax numerators
  __shared__ unsigned soff[4][CAP];   // [wave][edge] feat byte offsets
  __shared__ unsigned seid[4][CAP];   // [wave][edge] edge ids
  __shared__ float sinv[4][4];        // [wave][head] inverse denominators
  int p = blockIdx.y;
  int tid = threadIdx.x;
  int wv = tid >> 6, lane = tid & 63;
  int node = blockIdx.x * 4 + wv;
  int b = p * N_NODES + node;
  int half = lane >> 5, lane32 = lane & 31;
  int head = lane32 >> 3;        // phase-B head: cols lane32*8..+7 in head lane32>>3
  int m = cnt[b];
  if (m > CAP) m = CAP;
  const float* elp = el + (size_t)p * N_NODES * 4;
  float* erdp = erd + (size_t)p * N_NODES * 8;
  const unsigned* sl = slots + (size_t)b * CAP;
  const int* srcp = src + (size_t)p * N_EDGES;
  const char* fp_ = (const char*)featbf + (size_t)p * N_NODES * IN_F * 2 + lane32 * 16;

  // ---- phase A: lanes (headA=lane>>4, e0=lane&15) cover all (head, edge) pairs ----
  {
    int headA = lane >> 4;
    float ern = erdp[(size_t)node * 8 + headA];
    for (int e = lane & 15; e < m; e += 16) {
      unsigned eid = sl[e];
      int s = srcp[eid];
      if (headA == 0) { soff[wv][e] = (unsigned)s * (unsigned)(IN_F * 2); seid[wv][e] = eid; }
      float ev = elp[s * 4 + headA] + ern;
      ev = ev > 0.f ? ev : NEG_SLOPE * ev;
      xs[wv][headA][e] = __expf(ev);
    }
  }
  // same-wave LDS producer->consumer: in-order DS pipe, compiler waitcnts; no barrier.

  // ---- phase B: this half's edges (parity = half), 4-deep unroll, dwordx4 loads ----
  float a0 = 0.f, a1 = 0.f, a2 = 0.f, a3 = 0.f;
  float a4 = 0.f, a5 = 0.f, a6 = 0.f, a7 = 0.f, den = 0.f;
  int i = half;
  for (; i + 6 < m; i += 8) {
    unsigned o0 = soff[wv][i], o1 = soff[wv][i + 2], o2 = soff[wv][i + 4], o3 = soff[wv][i + 6];
    float x0 = xs[wv][head][i], x1 = xs[wv][head][i + 2];
    float x2 = xs[wv][head][i + 4], x3 = xs[wv][head][i + 6];
    uint4 f0 = *(const uint4*)(fp_ + o0);
    uint4 f1 = *(const uint4*)(fp_ + o1);
    uint4 f2 = *(const uint4*)(fp_ + o2);
    uint4 f3 = *(const uint4*)(fp_ + o3);
    den += (x0 + x1) + (x2 + x3);
    a0 += x0 * bfl(f0.x) + x1 * bfl(f1.x) + x2 * bfl(f2.x) + x3 * bfl(f3.x);
    a1 += x0 * bfh(f0.x) + x1 * bfh(f1.x) + x2 * bfh(f2.x) + x3 * bfh(f3.x);
    a2 += x0 * bfl(f0.y) + x1 * bfl(f1.y) + x2 * bfl(f2.y) + x3 * bfl(f3.y);
    a3 += x0 * bfh(f0.y) + x1 * bfh(f1.y) + x2 * bfh(f2.y) + x3 * bfh(f3.y);
    a4 += x0 * bfl(f0.z) + x1 * bfl(f1.z) + x2 * bfl(f2.z) + x3 * bfl(f3.z);
    a5 += x0 * bfh(f0.z) + x1 * bfh(f1.z) + x2 * bfh(f2.z) + x3 * bfh(f3.z);
    a6 += x0 * bfl(f0.w) + x1 * bfl(f1.w) + x2 * bfl(f2.w) + x3 * bfl(f3.w);
    a7 += x0 * bfh(f0.w) + x1 * bfh(f1.w) + x2 * bfh(f2.w) + x3 * bfh(f3.w);
  }
  for (; i + 2 < m; i += 4) {
    unsigned o0 = soff[wv][i], o1 = soff[wv][i + 2];
    float x0 = xs[wv][head][i], x1 = xs[wv][head][i + 2];
    uint4 f0 = *(const uint4*)(fp_ + o0);
    uint4 f1 = *(const uint4*)(fp_ + o1);
    den += x0 + x1;
    a0 += x0 * bfl(f0.x) + x1 * bfl(f1.x);
    a1 += x0 * bfh(f0.x) + x1 * bfh(f1.x);
    a2 += x0 * bfl(f0.y) + x1 * bfl(f1.y);
    a3 += x0 * bfh(f0.y) + x1 * bfh(f1.y);
    a4 += x0 * bfl(f0.z) + x1 * bfl(f1.z);
    a5 += x0 * bfh(f0.z) + x1 * bfh(f1.z);
    a6 += x0 * bfl(f0.w) + x1 * bfl(f1.w);
    a7 += x0 * bfh(f0.w) + x1 * bfh(f1.w);
  }
  for (; i < m; i += 2) {
    unsigned o0 = soff[wv][i];
    float x0 = xs[wv][head][i];
    uint4 f = *(const uint4*)(fp_ + o0);
    den += x0;
    a0 += x0 * bfl(f.x);
    a1 += x0 * bfh(f.x);
    a2 += x0 * bfl(f.y);
    a3 += x0 * bfh(f.y);
    a4 += x0 * bfl(f.z);
    a5 += x0 * bfh(f.z);
    a6 += x0 * bfl(f.w);
    a7 += x0 * bfh(f.w);
  }

  // ---- merge halves + epilogue ----
  den += __shfl_xor(den, 32);
  a0 += __shfl_xor(a0, 32);
  a1 += __shfl_xor(a1, 32);
  a2 += __shfl_xor(a2, 32);
  a3 += __shfl_xor(a3, 32);
  a4 += __shfl_xor(a4, 32);
  a5 += __shfl_xor(a5, 32);
  a6 += __shfl_xor(a6, 32);
  a7 += __shfl_xor(a7, 32);
  float inv = den > 0.f ? 1.f / den : 0.f;
  sinv[wv][head] = inv;   // all lanes of a head write the identical value
  if (half == 0) {
    float o0 = fmaxf(a0 * inv, 0.f), o1 = fmaxf(a1 * inv, 0.f);
    float o2 = fmaxf(a2 * inv, 0.f), o3 = fmaxf(a3 * inv, 0.f);
    float o4 = fmaxf(a4 * inv, 0.f), o5 = fmaxf(a5 * inv, 0.f);
    float o6 = fmaxf(a6 * inv, 0.f), o7 = fmaxf(a7 * inv, 0.f);
    uint4 u;
    u.x = (unsigned)f2bf(o0) | ((unsigned)f2bf(o1) << 16);
    u.y = (unsigned)f2bf(o2) | ((unsigned)f2bf(o3) << 16);
    u.z = (unsigned)f2bf(o4) | ((unsigned)f2bf(o5) << 16);
    u.w = (unsigned)f2bf(o6) | ((unsigned)f2bf(o7) << 16);
    *(uint4*)(outbuf + (size_t)b * IN_F + lane32 * 8) = u;
    if ((lane32 & 7) == 0) erdp[(size_t)node * 8 + 4 + head] = inv;
  }

  // ---- phase C: attention coefficients (k_attn fused) ----
  for (int e = lane; e < m; e += 64) {
    float am = 0.25f * (xs[wv][0][e] * sinv[wv][0] + xs[wv][1][e] * sinv[wv][1] +
                        xs[wv][2][e] * sinv[wv][2] + xs[wv][3][e] * sinv[wv][3]);
    attn_out[(size_t)p * N_EDGES + seid[wv][e]] = am;
  }
}

// ---------------- BN column stats, all 3 paths in one pass (h read once) ----------------
__global__ __launch_bounds__(256) void k_bnstats3(const unsigned short* __restrict__ outbuf,
                                                  const float* __restrict__ h,
                                                  float* __restrict__ colsum, float* __restrict__ colsq) {
  int t = threadIdx.x;
  float s0 = 0.f, q0 = 0.f, s1 = 0.f, q1 = 0.f, s2 = 0.f, q2 = 0.f;
  for (int r = blockIdx.x; r < N_NODES; r += gridDim.x) {
    float hv = h[(size_t)r * IN_F + t];
    float v0 = bf2f(outbuf[(size_t)r * IN_F + t]) + hv;
    float v1 = bf2f(outbuf[((size_t)N_NODES + r) * IN_F + t]) + hv;
    float v2 = bf2f(outbuf[((size_t)2 * N_NODES + r) * IN_F + t]) + hv;
    s0 += v0; q0 += v0 * v0;
    s1 += v1; q1 += v1 * v1;
    s2 += v2; q2 += v2 * v2;
  }
  atomicAdd(&colsum[t], s0);
  atomicAdd(&colsq[t], q0);
  atomicAdd(&colsum[256 + t], s1);
  atomicAdd(&colsq[256 + t], q1);
  atomicAdd(&colsum[512 + t], s2);
  atomicAdd(&colsq[512 + t], q2);
}

// ---------------- BN apply + semantic pooling + out_w, one pass ----------------
__global__ __launch_bounds__(256) void k_bnapply3(const unsigned short* __restrict__ outbuf,
                                                  const float* __restrict__ h,
                                                  const float* __restrict__ colsum, const float* __restrict__ colsq,
                                                  const float* __restrict__ gamma, const float* __restrict__ beta,
                                                  const float* __restrict__ pmask,
                                                  float* __restrict__ pooled,
                                                  float* __restrict__ wout) {
  __shared__ float spm[3];
  int n = blockIdx.x, t = threadIdx.x;
  if (t < 3) spm[t] = pmask[n * 3 + t];
  __syncthreads();
  float ssum = spm[0] + spm[1] + spm[2];
  if (t < 3) wout[n * 3 + t] = spm[t] / ssum;
  const float invN = 1.f / (float)N_NODES;
  float hv = h[(size_t)n * IN_F + t];
  float g = gamma[t], bt = beta[t];
  float pv = 0.f;
  #pragma unroll
  for (int p = 0; p < 3; ++p) {
    float mu = colsum[p * 256 + t] * invN;
    float var = colsq[p * 256 + t] * invN - mu * mu;
    float rs = rsqrtf(var + BN_EPS);
    float v = bf2f(outbuf[((size_t)p * N_NODES + n) * IN_F + t]) + hv;
    float emb = g * (v - mu) * rs + bt;
    pv += (spm[p] / ssum) * emb;
  }
  pooled[(size_t)n * IN_F + t] = pv;
}

extern "C" void kernel_launch(void* const* d_in, const int* in_sizes, int n_in,
                              void* d_out, int out_size, void* d_ws, size_t ws_size,
                              hipStream_t stream) {
  const float* h     = (const float*)d_in[0];
  const float* pmask = (const float*)d_in[1];
  const int*   src   = (const int*)d_in[2];
  const int*   dst   = (const int*)d_in[3];
  const float* fcw   = (const float*)d_in[4];
  const float* attl  = (const float*)d_in[5];
  const float* attr  = (const float*)d_in[6];
  const float* gamma = (const float*)d_in[7];
  const float* beta  = (const float*)d_in[8];

  float* out_pooled = (float*)d_out;
  float* out_w = out_pooled + (size_t)N_NODES * IN_F;
  float* out_attn = out_w + (size_t)N_NODES * N_PATHS;

  char* wp = (char*)d_ws;
  auto carve = [&](size_t bytes) {
    char* r = wp;
    wp += (bytes + 255) & ~(size_t)255;
    return r;
  };
  unsigned short* hbf    = (unsigned short*)carve((size_t)N_NODES * IN_F * 2);          // 25.6 MB
  unsigned short* featbf = (unsigned short*)carve((size_t)N_PATHS * N_NODES * IN_F * 2); // 76.8 MB
  unsigned short* wbf    = (unsigned short*)carve((size_t)N_PATHS * IN_F * IN_F * 2);    // 0.4 MB
  unsigned short* outbuf = (unsigned short*)carve((size_t)N_PATHS * N_NODES * IN_F * 2); // 76.8 MB
  // grec (10.8 MB) is dead after k_fine; el (2.4) + erd (4.8) alias onto it
  char* grec_base = carve((size_t)NB_TOT * REC_CAP * 4);
  unsigned* grec = (unsigned*)grec_base;
  float* el  = (float*)grec_base;
  float* erd = el + (size_t)N_PATHS * N_NODES * 4;
  unsigned* slots = (unsigned*)carve((size_t)N_PATHS * N_NODES * CAP * 4);               // 28.8 MB
  int* cnt = (int*)carve((size_t)N_PATHS * N_NODES * 4);                                  // 0.6 MB
  // zero-region: gcurP (padded), colsum[3][256], colsq[3][256]
  char* zbase = wp;
  unsigned* gcurP = (unsigned*)carve((size_t)NB_TOT * 16 * 4);
  float* colsum = (float*)carve((size_t)N_PATHS * IN_F * 4);
  float* colsq  = (float*)carve((size_t)N_PATHS * IN_F * 4);
  int zero_words = (int)((wp - zbase) / 4);

  k_convert_h<<<(N_NODES * IN_F) / 1024, 256, 0, stream>>>(h, hbf);
  k_convert_w<<<N_PATHS * 64, 256, 0, stream>>>(fcw, wbf);
  k_zero<<<(zero_words + 255) / 256, 256, 0, stream>>>((unsigned*)zbase, zero_words);
  k_bin<<<BIN_BLOCKS, 256, 0, stream>>>(src, dst, gcurP, grec);
  k_fine<<<NB_TOT, 1024, 0, stream>>>(gcurP, grec, slots, cnt);
  k_gemm<<<dim3((N_NODES + 63) / 64, N_PATHS), 256, 0, stream>>>(hbf, wbf, attl, attr,
                                                                 featbf, el, erd);
  k_gather<<<dim3(N_NODES / 4, N_PATHS), 256, 0, stream>>>(cnt, slots, src, el, erd,
                                                           featbf, outbuf, out_attn);
  k_bnstats3<<<512, 256, 0, stream>>>(outbuf, h, colsum, colsq);
  k_bnapply3<<<N_NODES, 256, 0, stream>>>(outbuf, h, colsum, colsq, gamma, beta, pmask,
                                          out_pooled, out_w);
}

// Round 7
// 539.891 us; speedup vs baseline: 1.2693x; 1.1342x over previous
//
#include <hip/hip_runtime.h>
#include <stdint.h>

#define N_NODES 50000
#define N_EDGES 800000
#define N_PATHS 3
#define N_HEADS 4
#define IN_F 256
#define BN_EPS 1e-5f
#define NEG_SLOPE 0.2f
#define CAP 48           // slot capacity per node; Poisson(16) => P(deg>48) ~ 3e-11
#define NB_PER_PATH 49   // coarse buckets of 1024 nodes
#define NB_TOT (N_PATHS * NB_PER_PATH)  // 147
#define REC_CAP 18432
#define BIN_EPB 4096
#define TOT_EDGES (N_PATHS * N_EDGES)   // 2400000
#define BIN_BLOCKS ((TOT_EDGES + BIN_EPB - 1) / BIN_EPB)  // 586

typedef short bf16x8 __attribute__((ext_vector_type(8)));
typedef float f32x4 __attribute__((ext_vector_type(4)));

__device__ inline unsigned short f2bf(float f) {
  unsigned u = __float_as_uint(f);
  unsigned r = (u + 0x7FFFu + ((u >> 16) & 1u)) >> 16;
  return (unsigned short)r;
}
__device__ inline float bf2f(unsigned short s) {
  return __uint_as_float(((unsigned)s) << 16);
}
__device__ inline float bfl(unsigned u) { return __uint_as_float(u << 16); }
__device__ inline float bfh(unsigned u) { return __uint_as_float(u & 0xFFFF0000u); }

// ---------------- zero fill ----------------
__global__ __launch_bounds__(256) void k_zero(unsigned* p, int nwords) {
  int i = blockIdx.x * 256 + threadIdx.x;
  if (i < nwords) p[i] = 0u;
}

// ---------------- W -> bf16, transposed to [n][k], all paths ----------------
__global__ __launch_bounds__(256) void k_convert_w(const float* __restrict__ fcw,
                                                   unsigned short* __restrict__ wbf) {
  __shared__ float sh[32][33];
  int bt = blockIdx.x;
  int p = bt >> 6;
  int tile = bt & 63;
  int tk = tile >> 3, tn = tile & 7;
  const float* base = fcw + (size_t)p * IN_F * IN_F;
  unsigned short* ob = wbf + (size_t)p * IN_F * IN_F;
  int c = threadIdx.x & 31, r0 = threadIdx.x >> 5;
  #pragma unroll
  for (int it = 0; it < 4; ++it) {
    int r = r0 + it * 8;
    sh[r][c] = base[(size_t)(tk * 32 + r) * IN_F + tn * 32 + c];
  }
  __syncthreads();
  #pragma unroll
  for (int it = 0; it < 4; ++it) {
    int r = r0 + it * 8;
    ob[(size_t)(tn * 32 + r) * IN_F + tk * 32 + c] = f2bf(sh[c][r]);
  }
}

// ---------------- bin phase 1: LDS histogram -> few global atomics -> coalesced record runs ----------------
__global__ __launch_bounds__(256) void k_bin(const int* __restrict__ src, const int* __restrict__ dst,
                                             unsigned* __restrict__ gcurP, unsigned* __restrict__ grec) {
  __shared__ unsigned hist[NB_TOT];
  __shared__ unsigned lbase[NB_TOT];
  __shared__ unsigned gbase[NB_TOT];
  __shared__ unsigned lcur[NB_TOT];
  __shared__ unsigned scanbuf[256];
  __shared__ unsigned char sbuck[BIN_EPB];
  __shared__ unsigned stage[BIN_EPB];
  int t = threadIdx.x;
  int base = blockIdx.x * BIN_EPB;
  for (int i = t; i < NB_TOT; i += 256) { hist[i] = 0u; lcur[i] = 0u; }
  __syncthreads();

  unsigned rec[16];
  int bk[16];
  #pragma unroll
  for (int k = 0; k < 16; ++k) {
    int gid = base + t + k * 256;
    bk[k] = -1;
    if (gid < TOT_EDGES) {
      int s = src[gid], d = dst[gid];
      int p = (gid >= 2 * N_EDGES) ? 2 : ((gid >= N_EDGES) ? 1 : 0);
      int b = p * NB_PER_PATH + (d >> 10);
      bk[k] = b;
      rec[k] = (unsigned)s | ((unsigned)(d & 1023) << 17);
      atomicAdd(&hist[b], 1u);
    }
  }
  __syncthreads();
  for (int i = t; i < NB_TOT; i += 256)
    gbase[i] = hist[i] ? atomicAdd(&gcurP[i * 16], hist[i]) : 0u;
  scanbuf[t] = (t < NB_TOT) ? hist[t] : 0u;
  __syncthreads();
  for (int off = 1; off < 256; off <<= 1) {
    unsigned v = (t >= off) ? scanbuf[t - off] : 0u;
    __syncthreads();
    scanbuf[t] += v;
    __syncthreads();
  }
  if (t < NB_TOT) lbase[t] = scanbuf[t] - hist[t];
  __syncthreads();
  #pragma unroll
  for (int k = 0; k < 16; ++k) {
    if (bk[k] >= 0) {
      int b = bk[k];
      unsigned pos = atomicAdd(&lcur[b], 1u) + lbase[b];
      stage[pos] = rec[k];
      sbuck[pos] = (unsigned char)b;
    }
  }
  __syncthreads();
  int nblk = TOT_EDGES - base;
  if (nblk > BIN_EPB) nblk = BIN_EPB;
  for (int i = t; i < nblk; i += 256) {
    int b = sbuck[i];
    unsigned off = (unsigned)i - lbase[b];
    unsigned gpos = gbase[b] + off;
    if (gpos < REC_CAP) grec[(size_t)b * REC_CAP + gpos] = stage[i];
  }
}

// ---------------- bin phase 2: per coarse bucket, LDS cursors -> u16 slots + counts ----------------
__global__ __launch_bounds__(1024) void k_fine(const unsigned* __restrict__ gcurP,
                                               const unsigned* __restrict__ grec,
                                               unsigned short* __restrict__ slots,
                                               int* __restrict__ cnt) {
  __shared__ unsigned cur[1024];
  int b = blockIdx.x;
  int p = b / NB_PER_PATH;
  int nb0 = (b % NB_PER_PATH) << 10;
  int t = threadIdx.x;
  cur[t] = 0u;
  __syncthreads();
  unsigned M = gcurP[b * 16];
  if (M > REC_CAP) M = REC_CAP;
  const unsigned* rb = grec + (size_t)b * REC_CAP;
  for (unsigned i = t; i < M; i += 1024) {
    unsigned r = rb[i];
    int node = r >> 17;
    int srcv = r & 0x1FFFF;
    unsigned pos = atomicAdd(&cur[node], 1u);
    if (pos < CAP)
      slots[((size_t)(p * N_NODES + nb0 + node)) * CAP + pos] = (unsigned short)srcv;
  }
  __syncthreads();
  int node = nb0 + t;
  if (node < N_NODES) cnt[p * N_NODES + node] = (int)cur[t];
}

// ---------------- fused GEMM (all paths): feat + el/er epilogue ----------------
// R7: stages A directly from f32 h with inline bf16 conversion (k_convert_h
// deleted; same total bytes, one fewer full pass + launch + 25.6MB buffer).
__global__ __launch_bounds__(256) void k_gemm(const float* __restrict__ h,
                                              const unsigned short* __restrict__ wbf,
                                              const float* __restrict__ attl,
                                              const float* __restrict__ attr,
                                              unsigned short* __restrict__ featbf,
                                              float* __restrict__ el,
                                              float* __restrict__ erd) {
  __shared__ unsigned short As[64 * 264];
  __shared__ unsigned short Bs[64 * 264];
  __shared__ float sal[256];
  __shared__ float sar[256];
  int m0 = blockIdx.x * 64;
  int p = blockIdx.y;
  int tid = threadIdx.x;
  const unsigned short* wptr = wbf + (size_t)p * IN_F * IN_F;

  sal[tid] = attl[p * 256 + tid];
  sar[tid] = attr[p * 256 + tid];
  for (int i = tid; i < 2048; i += 256) {
    int r = i >> 5, g = i & 31;
    int gr = m0 + r;
    uint4 o = make_uint4(0, 0, 0, 0);
    if (gr < N_NODES) {
      const float* hp = h + (size_t)gr * IN_F + g * 8;
      float4 v0 = *(const float4*)hp;
      float4 v1 = *(const float4*)(hp + 4);
      o.x = (unsigned)f2bf(v0.x) | ((unsigned)f2bf(v0.y) << 16);
      o.y = (unsigned)f2bf(v0.z) | ((unsigned)f2bf(v0.w) << 16);
      o.z = (unsigned)f2bf(v1.x) | ((unsigned)f2bf(v1.y) << 16);
      o.w = (unsigned)f2bf(v1.z) | ((unsigned)f2bf(v1.w) << 16);
    }
    *(uint4*)(&As[r * 264 + g * 8]) = o;
  }

  int wv = tid >> 6, lane = tid & 63;
  int l15 = lane & 15, quad = lane >> 4;
  const unsigned short* arow = &As[(wv * 16 + l15) * 264];
  size_t featbase = (size_t)p * N_NODES * IN_F;
  float* elp = el + (size_t)p * N_NODES * 4;
  float* erdp = erd + (size_t)p * N_NODES * 8;

  for (int c = 0; c < 4; ++c) {
    __syncthreads();  // A ready (c=0) / prev-chunk Bs reads done (c>0)
    for (int i = tid; i < 2048; i += 256) {
      int r = i >> 5, g = i & 31;
      *(uint4*)(&Bs[r * 264 + g * 8]) =
          *(const uint4*)(wptr + (size_t)(c * 64 + r) * IN_F + g * 8);
    }
    __syncthreads();

    f32x4 acc[4];
    #pragma unroll
    for (int i = 0; i < 4; ++i) acc[i] = (f32x4){0.f, 0.f, 0.f, 0.f};
    #pragma unroll
    for (int kb = 0; kb < 8; ++kb) {
      bf16x8 a = *(const bf16x8*)(arow + kb * 32 + quad * 8);
      #pragma unroll
      for (int nn = 0; nn < 4; ++nn) {
        bf16x8 b = *(const bf16x8*)(&Bs[(nn * 16 + l15) * 264 + kb * 32 + quad * 8]);
        acc[nn] = __builtin_amdgcn_mfma_f32_16x16x32_bf16(a, b, acc[nn], 0, 0, 0);
      }
    }
    // feat store (C/D layout: col = lane&15, row = quad*4+reg)
    #pragma unroll
    for (int nn = 0; nn < 4; ++nn)
      #pragma unroll
      for (int rg = 0; rg < 4; ++rg) {
        int grow = m0 + wv * 16 + quad * 4 + rg;
        if (grow < N_NODES)
          featbf[featbase + (size_t)grow * IN_F + c * 64 + nn * 16 + l15] = f2bf(acc[nn][rg]);
      }
    // el/er for head c: per-row dot over the 64 chunk cols
    #pragma unroll
    for (int rg = 0; rg < 4; ++rg) {
      float a = 0.f, b = 0.f;
      #pragma unroll
      for (int nn = 0; nn < 4; ++nn) {
        float v = acc[nn][rg];
        int col = c * 64 + nn * 16 + l15;
        a += v * sal[col];
        b += v * sar[col];
      }
      a += __shfl_xor(a, 1); a += __shfl_xor(a, 2); a += __shfl_xor(a, 4); a += __shfl_xor(a, 8);
      b += __shfl_xor(b, 1); b += __shfl_xor(b, 2); b += __shfl_xor(b, 4); b += __shfl_xor(b, 8);
      int grow = m0 + wv * 16 + quad * 4 + rg;
      if (l15 == 0 && grow < N_NODES) {
        elp[(size_t)grow * 4 + c] = a;
        erdp[(size_t)grow * 8 + c] = b;
      }
    }
  }
}

// ---------------- gather: wave-per-node, half-wave-per-edge, barrier-free ----------------
// R4 version (measured floor ~171us): 1.23 GB mandatory random 512B row reads.
__global__ __launch_bounds__(256) void k_gather(const int* __restrict__ cnt,
                                                const unsigned short* __restrict__ slots,
                                                const float* __restrict__ el,
                                                float* __restrict__ erd,
                                                const unsigned short* __restrict__ featbf,
                                                unsigned short* __restrict__ outbuf) {
  __shared__ float xs[4][4][CAP];     // [wave][head][edge] softmax numerators
  __shared__ unsigned soff[4][CAP];   // [wave][edge] feat byte offsets
  int p = blockIdx.y;
  int tid = threadIdx.x;
  int wv = tid >> 6, lane = tid & 63;
  int node = blockIdx.x * 4 + wv;
  int b = p * N_NODES + node;
  int half = lane >> 5, lane32 = lane & 31;
  int head = lane32 >> 3;        // phase-B head: cols lane32*8..+7 in head lane32>>3
  int m = cnt[b];
  if (m > CAP) m = CAP;
  const float* elp = el + (size_t)p * N_NODES * 4;
  float* erdp = erd + (size_t)p * N_NODES * 8;
  const unsigned short* sl = slots + (size_t)b * CAP;
  const char* fp_ = (const char*)featbf + (size_t)p * N_NODES * IN_F * 2 + lane32 * 16;

  // ---- phase A: lanes (headA=lane>>4, e0=lane&15) cover all (head, edge) pairs ----
  {
    int headA = lane >> 4;
    float ern = erdp[(size_t)node * 8 + headA];
    for (int e = lane & 15; e < m; e += 16) {
      int s = (int)sl[e];
      if (headA == 0) soff[wv][e] = (unsigned)s * (unsigned)(IN_F * 2);
      float ev = elp[s * 4 + headA] + ern;
      ev = ev > 0.f ? ev : NEG_SLOPE * ev;
      xs[wv][headA][e] = __expf(ev);
    }
  }
  // same-wave LDS producer->consumer: in-order DS pipe, compiler waitcnts; no barrier.

  // ---- phase B: this half's edges (parity = half), 4-deep unroll, dwordx4 loads ----
  float a0 = 0.f, a1 = 0.f, a2 = 0.f, a3 = 0.f;
  float a4 = 0.f, a5 = 0.f, a6 = 0.f, a7 = 0.f, den = 0.f;
  int i = half;
  for (; i + 6 < m; i += 8) {
    unsigned o0 = soff[wv][i], o1 = soff[wv][i + 2], o2 = soff[wv][i + 4], o3 = soff[wv][i + 6];
    float x0 = xs[wv][head][i], x1 = xs[wv][head][i + 2];
    float x2 = xs[wv][head][i + 4], x3 = xs[wv][head][i + 6];
    uint4 f0 = *(const uint4*)(fp_ + o0);
    uint4 f1 = *(const uint4*)(fp_ + o1);
    uint4 f2 = *(const uint4*)(fp_ + o2);
    uint4 f3 = *(const uint4*)(fp_ + o3);
    den += (x0 + x1) + (x2 + x3);
    a0 += x0 * bfl(f0.x) + x1 * bfl(f1.x) + x2 * bfl(f2.x) + x3 * bfl(f3.x);
    a1 += x0 * bfh(f0.x) + x1 * bfh(f1.x) + x2 * bfh(f2.x) + x3 * bfh(f3.x);
    a2 += x0 * bfl(f0.y) + x1 * bfl(f1.y) + x2 * bfl(f2.y) + x3 * bfl(f3.y);
    a3 += x0 * bfh(f0.y) + x1 * bfh(f1.y) + x2 * bfh(f2.y) + x3 * bfh(f3.y);
    a4 += x0 * bfl(f0.z) + x1 * bfl(f1.z) + x2 * bfl(f2.z) + x3 * bfl(f3.z);
    a5 += x0 * bfh(f0.z) + x1 * bfh(f1.z) + x2 * bfh(f2.z) + x3 * bfh(f3.z);
    a6 += x0 * bfl(f0.w) + x1 * bfl(f1.w) + x2 * bfl(f2.w) + x3 * bfl(f3.w);
    a7 += x0 * bfh(f0.w) + x1 * bfh(f1.w) + x2 * bfh(f2.w) + x3 * bfh(f3.w);
  }
  for (; i + 2 < m; i += 4) {
    unsigned o0 = soff[wv][i], o1 = soff[wv][i + 2];
    float x0 = xs[wv][head][i], x1 = xs[wv][head][i + 2];
    uint4 f0 = *(const uint4*)(fp_ + o0);
    uint4 f1 = *(const uint4*)(fp_ + o1);
    den += x0 + x1;
    a0 += x0 * bfl(f0.x) + x1 * bfl(f1.x);
    a1 += x0 * bfh(f0.x) + x1 * bfh(f1.x);
    a2 += x0 * bfl(f0.y) + x1 * bfl(f1.y);
    a3 += x0 * bfh(f0.y) + x1 * bfh(f1.y);
    a4 += x0 * bfl(f0.z) + x1 * bfl(f1.z);
    a5 += x0 * bfh(f0.z) + x1 * bfh(f1.z);
    a6 += x0 * bfl(f0.w) + x1 * bfl(f1.w);
    a7 += x0 * bfh(f0.w) + x1 * bfh(f1.w);
  }
  for (; i < m; i += 2) {
    unsigned o0 = soff[wv][i];
    float x0 = xs[wv][head][i];
    uint4 f = *(const uint4*)(fp_ + o0);
    den += x0;
    a0 += x0 * bfl(f.x);
    a1 += x0 * bfh(f.x);
    a2 += x0 * bfl(f.y);
    a3 += x0 * bfh(f.y);
    a4 += x0 * bfl(f.z);
    a5 += x0 * bfh(f.z);
    a6 += x0 * bfl(f.w);
    a7 += x0 * bfh(f.w);
  }

  // ---- merge halves + epilogue ----
  den += __shfl_xor(den, 32);
  a0 += __shfl_xor(a0, 32);
  a1 += __shfl_xor(a1, 32);
  a2 += __shfl_xor(a2, 32);
  a3 += __shfl_xor(a3, 32);
  a4 += __shfl_xor(a4, 32);
  a5 += __shfl_xor(a5, 32);
  a6 += __shfl_xor(a6, 32);
  a7 += __shfl_xor(a7, 32);
  if (half == 0) {
    float inv = den > 0.f ? 1.f / den : 0.f;
    float o0 = fmaxf(a0 * inv, 0.f), o1 = fmaxf(a1 * inv, 0.f);
    float o2 = fmaxf(a2 * inv, 0.f), o3 = fmaxf(a3 * inv, 0.f);
    float o4 = fmaxf(a4 * inv, 0.f), o5 = fmaxf(a5 * inv, 0.f);
    float o6 = fmaxf(a6 * inv, 0.f), o7 = fmaxf(a7 * inv, 0.f);
    uint4 u;
    u.x = (unsigned)f2bf(o0) | ((unsigned)f2bf(o1) << 16);
    u.y = (unsigned)f2bf(o2) | ((unsigned)f2bf(o3) << 16);
    u.z = (unsigned)f2bf(o4) | ((unsigned)f2bf(o5) << 16);
    u.w = (unsigned)f2bf(o6) | ((unsigned)f2bf(o7) << 16);
    *(uint4*)(outbuf + (size_t)b * IN_F + lane32 * 8) = u;
    if ((lane32 & 7) == 0) erdp[(size_t)node * 8 + 4 + head] = inv;
  }
}

// ---------------- attention coefficients (all paths): alpha = exp(e)*invdenom, mean heads ----------------
// Coalesced eid-order writes; el/erd random reads are L2-resident (0.8/1.6 MB per path).
__global__ __launch_bounds__(256) void k_attn(const int* __restrict__ src, const int* __restrict__ dst,
                                              const float* __restrict__ el,
                                              const float* __restrict__ erd,
                                              float* __restrict__ attn_out) {
  int eid = blockIdx.x * 256 + threadIdx.x;
  int p = eid / N_EDGES;
  int s = src[eid], t = dst[eid];
  const float* elp = el + (size_t)p * N_NODES * 4;
  const float* erdp = erd + (size_t)p * N_NODES * 8;
  float4 a = *(const float4*)(elp + (size_t)s * 4);
  float4 b = *(const float4*)(erdp + (size_t)t * 8);
  float4 idn = *(const float4*)(erdp + (size_t)t * 8 + 4);
  float4 e;
  e.x = a.x + b.x; e.x = e.x > 0.f ? e.x : NEG_SLOPE * e.x;
  e.y = a.y + b.y; e.y = e.y > 0.f ? e.y : NEG_SLOPE * e.y;
  e.z = a.z + b.z; e.z = e.z > 0.f ? e.z : NEG_SLOPE * e.z;
  e.w = a.w + b.w; e.w = e.w > 0.f ? e.w : NEG_SLOPE * e.w;
  attn_out[eid] = 0.25f * (__expf(e.x) * idn.x + __expf(e.y) * idn.y +
                           __expf(e.z) * idn.z + __expf(e.w) * idn.w);
}

// ---------------- BN column stats, all 3 paths in one pass (h read once) ----------------
__global__ __launch_bounds__(256) void k_bnstats3(const unsigned short* __restrict__ outbuf,
                                                  const float* __restrict__ h,
                                                  float* __restrict__ colsum, float* __restrict__ colsq) {
  int t = threadIdx.x;
  float s0 = 0.f, q0 = 0.f, s1 = 0.f, q1 = 0.f, s2 = 0.f, q2 = 0.f;
  for (int r = blockIdx.x; r < N_NODES; r += gridDim.x) {
    float hv = h[(size_t)r * IN_F + t];
    float v0 = bf2f(outbuf[(size_t)r * IN_F + t]) + hv;
    float v1 = bf2f(outbuf[((size_t)N_NODES + r) * IN_F + t]) + hv;
    float v2 = bf2f(outbuf[((size_t)2 * N_NODES + r) * IN_F + t]) + hv;
    s0 += v0; q0 += v0 * v0;
    s1 += v1; q1 += v1 * v1;
    s2 += v2; q2 += v2 * v2;
  }
  atomicAdd(&colsum[t], s0);
  atomicAdd(&colsq[t], q0);
  atomicAdd(&colsum[256 + t], s1);
  atomicAdd(&colsq[256 + t], q1);
  atomicAdd(&colsum[512 + t], s2);
  atomicAdd(&colsq[512 + t], q2);
}

// ---------------- BN apply + semantic pooling + out_w, one pass ----------------
__global__ __launch_bounds__(256) void k_bnapply3(const unsigned short* __restrict__ outbuf,
                                                  const float* __restrict__ h,
                                                  const float* __restrict__ colsum, const float* __restrict__ colsq,
                                                  const float* __restrict__ gamma, const float* __restrict__ beta,
                                                  const float* __restrict__ pmask,
                                                  float* __restrict__ pooled,
                                                  float* __restrict__ wout) {
  __shared__ float spm[3];
  int n = blockIdx.x, t = threadIdx.x;
  if (t < 3) spm[t] = pmask[n * 3 + t];
  __syncthreads();
  float ssum = spm[0] + spm[1] + spm[2];
  if (t < 3) wout[n * 3 + t] = spm[t] / ssum;
  const float invN = 1.f / (float)N_NODES;
  float hv = h[(size_t)n * IN_F + t];
  float g = gamma[t], bt = beta[t];
  float pv = 0.f;
  #pragma unroll
  for (int p = 0; p < 3; ++p) {
    float mu = colsum[p * 256 + t] * invN;
    float var = colsq[p * 256 + t] * invN - mu * mu;
    float rs = rsqrtf(var + BN_EPS);
    float v = bf2f(outbuf[((size_t)p * N_NODES + n) * IN_F + t]) + hv;
    float emb = g * (v - mu) * rs + bt;
    pv += (spm[p] / ssum) * emb;
  }
  pooled[(size_t)n * IN_F + t] = pv;
}

extern "C" void kernel_launch(void* const* d_in, const int* in_sizes, int n_in,
                              void* d_out, int out_size, void* d_ws, size_t ws_size,
                              hipStream_t stream) {
  const float* h     = (const float*)d_in[0];
  const float* pmask = (const float*)d_in[1];
  const int*   src   = (const int*)d_in[2];
  const int*   dst   = (const int*)d_in[3];
  const float* fcw   = (const float*)d_in[4];
  const float* attl  = (const float*)d_in[5];
  const float* attr  = (const float*)d_in[6];
  const float* gamma = (const float*)d_in[7];
  const float* beta  = (const float*)d_in[8];

  float* out_pooled = (float*)d_out;
  float* out_w = out_pooled + (size_t)N_NODES * IN_F;
  float* out_attn = out_w + (size_t)N_NODES * N_PATHS;

  char* wp = (char*)d_ws;
  auto carve = [&](size_t bytes) {
    char* r = wp;
    wp += (bytes + 255) & ~(size_t)255;
    return r;
  };
  unsigned short* featbf = (unsigned short*)carve((size_t)N_PATHS * N_NODES * IN_F * 2); // 76.8 MB
  unsigned short* wbf    = (unsigned short*)carve((size_t)N_PATHS * IN_F * IN_F * 2);    // 0.4 MB
  unsigned short* outbuf = (unsigned short*)carve((size_t)N_PATHS * N_NODES * IN_F * 2); // 76.8 MB
  // grec (10.8 MB) is dead after k_fine; el (2.4) + erd (4.8) alias onto it
  char* grec_base = carve((size_t)NB_TOT * REC_CAP * 4);
  unsigned* grec = (unsigned*)grec_base;
  float* el  = (float*)grec_base;
  float* erd = el + (size_t)N_PATHS * N_NODES * 4;
  unsigned short* slots = (unsigned short*)carve((size_t)N_PATHS * N_NODES * CAP * 2);   // 14.4 MB
  int* cnt = (int*)carve((size_t)N_PATHS * N_NODES * 4);                                  // 0.6 MB
  // zero-region: gcurP (padded), colsum[3][256], colsq[3][256]
  char* zbase = wp;
  unsigned* gcurP = (unsigned*)carve((size_t)NB_TOT * 16 * 4);
  float* colsum = (float*)carve((size_t)N_PATHS * IN_F * 4);
  float* colsq  = (float*)carve((size_t)N_PATHS * IN_F * 4);
  int zero_words = (int)((wp - zbase) / 4);

  k_convert_w<<<N_PATHS * 64, 256, 0, stream>>>(fcw, wbf);
  k_zero<<<(zero_words + 255) / 256, 256, 0, stream>>>((unsigned*)zbase, zero_words);
  k_bin<<<BIN_BLOCKS, 256, 0, stream>>>(src, dst, gcurP, grec);
  k_fine<<<NB_TOT, 1024, 0, stream>>>(gcurP, grec, slots, cnt);
  k_gemm<<<dim3((N_NODES + 63) / 64, N_PATHS), 256, 0, stream>>>(h, wbf, attl, attr,
                                                                 featbf, el, erd);
  k_gather<<<dim3(N_NODES / 4, N_PATHS), 256, 0, stream>>>(cnt, slots, el, erd, featbf, outbuf);
  k_attn<<<TOT_EDGES / 256, 256, 0, stream>>>(src, dst, el, erd, out_attn);
  k_bnstats3<<<512, 256, 0, stream>>>(outbuf, h, colsum, colsq);
  k_bnapply3<<<N_NODES, 256, 0, stream>>>(outbuf, h, colsum, colsq, gamma, beta, pmask,
                                          out_pooled, out_w);
}